// Round 7
// baseline (630.602 us; speedup 1.0000x reference)
//
#include <hip/hip_runtime.h>
#include <hip/hip_bf16.h>

// ---------------------------------------------------------------------------
// GatedNetwork: N = 131072 nodes == edges, C = 256 channels.
// Factorization: e_out[k] = PR[row[k]] + PC[col[k]],
//   PR = h@A^T + e@D^T + (Ab+Db),  PC = h@B^T + e@C^T + (Bb+Cb)
// Pipeline (7 dispatches):
//   prep_weights (weights->tiled bf16, bias pack, idx-mode, zero stats+bar)
//   coop_sort    (zero cnt, hist, scan x3, scatter -- 1 kernel, spin barriers)
//   prep_he      (h,e -> tiled bf16)
//   gemm_fused   (GEMM1 PRPC 4096 blocks + GEMM2 VU 4096 blocks, one grid)
//   edge_stats   (BN batch stats, gathered)
//   gather_sig_T (sig -> accB bf16, colsum, Traw += sig*HV[col])
//   finalize     (outE = accB*iv ; outH = relu(HU + iv*Traw))
// ---------------------------------------------------------------------------

typedef __attribute__((ext_vector_type(8))) short bf16x8;
typedef __attribute__((ext_vector_type(4))) float f32x4;

__device__ __forceinline__ float b2f(unsigned int lo16) {
  union { unsigned int u; float f; } c; c.u = lo16 << 16; return c.f;
}
__device__ __forceinline__ float lof(unsigned int u) { return b2f(u & 0xffffu); }
__device__ __forceinline__ float hif(unsigned int u) { return b2f(u >> 16); }
__device__ __forceinline__ unsigned int f2b(float f) {  // RNE f32->bf16
  union { float f; unsigned int u; } c; c.f = f;
  unsigned int u = c.u;
  u += 0x7fffu + ((u >> 16) & 1u);
  return u >> 16;
}

// --- prep: f32 row-major [M][256] -> bf16 tiled [M/16][32][16][8] ----------
__device__ __forceinline__ void prep_chunk(const float* __restrict__ src,
                                           unsigned short* __restrict__ dst, int g) {
  int mtile = g >> 9;
  int rem = g & 511;
  int r = rem >> 5, k8 = rem & 31;
  const float4* s = reinterpret_cast<const float4*>(src + (((size_t)mtile * 16 + r) << 8) + k8 * 8);
  float4 v0 = s[0], v1 = s[1];
  uint4 o;
  o.x = f2b(v0.x) | (f2b(v0.y) << 16);
  o.y = f2b(v0.z) | (f2b(v0.w) << 16);
  o.z = f2b(v1.x) | (f2b(v1.y) << 16);
  o.w = f2b(v1.z) | (f2b(v1.w) << 16);
  *reinterpret_cast<uint4*>(dst + ((size_t)mtile * 512 + k8 * 16 + r) * 8) = o;
}

__global__ __launch_bounds__(256) void prep_he(const float* __restrict__ h,
                                               unsigned short* __restrict__ h_t,
                                               const float* __restrict__ e,
                                               unsigned short* __restrict__ e_t,
                                               int nChunksEach) {
  int g = blockIdx.x * 256 + threadIdx.x;
  if (g < nChunksEach) prep_chunk(h, h_t, g);
  else if (g < 2 * nChunksEach) prep_chunk(e, e_t, g - nChunksEach);
}

// weights -> tiled bf16; block 0 also: bias pack, idx-mode, zero stats + bar
__global__ __launch_bounds__(256) void prep_weights(
    const float* __restrict__ s0, const float* __restrict__ s1,
    const float* __restrict__ s2, const float* __restrict__ s3,
    const float* __restrict__ s4, const float* __restrict__ s5,
    unsigned short* __restrict__ W1h, unsigned short* __restrict__ W1e,
    unsigned short* __restrict__ W2t,
    const float* __restrict__ Ab, const float* __restrict__ Db,
    const float* __restrict__ Bb, const float* __restrict__ Cb,
    const float* __restrict__ Vb, const float* __restrict__ Ub,
    float* __restrict__ b1, float* __restrict__ b2,
    float* __restrict__ sums, float* __restrict__ sumsq,
    float* __restrict__ colsum, float* __restrict__ Traw,
    const int* __restrict__ ei, int* __restrict__ mode, int* __restrict__ bar) {
  int g = blockIdx.x * 256 + threadIdx.x;
  if (blockIdx.x == 0) {
    const int t = threadIdx.x;
    b1[t] = Ab[t] + Db[t];
    b1[256 + t] = Bb[t] + Cb[t];
    b2[t] = Vb[t];
    b2[256 + t] = Ub[t];
    sums[t] = 0.f; sumsq[t] = 0.f; colsum[t] = 0.f; Traw[t] = 0.f;
    if (t == 0) {
      int m = 0;
#pragma unroll
      for (int i = 1; i < 64; i += 2) m |= ei[i];
      *mode = (m == 0) ? 1 : 0;
      *bar = 0;
    }
  }
  int sel = g >> 13;
  int gg = g & 8191;
  const float* src; unsigned short* dst;
  switch (sel) {
    case 0: src = s0; dst = W1h; break;           // A
    case 1: src = s1; dst = W1h + 65536; break;   // B
    case 2: src = s2; dst = W1e; break;           // D
    case 3: src = s3; dst = W1e + 65536; break;   // C
    case 4: src = s4; dst = W2t; break;           // V
    default: src = s5; dst = W2t + 65536; break;  // U
  }
  prep_chunk(src, dst, gg);
}

// --- software grid barrier (all blocks co-resident by construction) --------
__device__ __forceinline__ void gridbar(int* bar, int target) {
  __syncthreads();
  if (threadIdx.x == 0) {
    __threadfence();                 // release: drain stores to L2
    atomicAdd(bar, 1);
    while (__hip_atomic_load(bar, __ATOMIC_RELAXED, __HIP_MEMORY_SCOPE_AGENT) < target) {
      __builtin_amdgcn_s_sleep(2);
    }
    __threadfence();                 // acquire: invalidate L1
  }
  __syncthreads();
}

// --- one-kernel counting sort: zero cnt -> hist -> scan -> scatter ---------
// 256 blocks x 256 thr, each thread owns 2 edges (grid-stride halves).
// __launch_bounds__(256,2): >=2 blocks/CU => 256 blocks always co-resident.
__global__ __launch_bounds__(256, 2) void coop_sort(
    const int* __restrict__ ei, const int* __restrict__ modep,
    int* __restrict__ cnt, int* __restrict__ bsum, int* __restrict__ baseA,
    int* __restrict__ rows_s, int* __restrict__ cols_s,
    int* __restrict__ bar, int Nn) {
  __shared__ int tmp[512];
  const int t = threadIdx.x;
  const int b = blockIdx.x;
  const int NB = 256;  // gridDim.x
  const int mode = *modep;
  int row[2], col[2];
  // phase 0: zero cnt + load this thread's 2 edge-index pairs
#pragma unroll
  for (int half = 0; half < 2; ++half) {
    const int g = (b + half * NB) * 256 + t;
    cnt[g] = 0;
    if (mode) { row[half] = ei[2 * g]; col[half] = ei[2 * (Nn + g)]; }
    else      { row[half] = ei[g];     col[half] = ei[Nn + g]; }
  }
  gridbar(bar, NB);
  // phase 1: histogram
  atomicAdd(&cnt[row[0]], 1);
  atomicAdd(&cnt[row[1]], 1);
  gridbar(bar, 2 * NB);
  // phase 2: per-256-chunk totals -> bsum[512]
  int own[2];
#pragma unroll
  for (int half = 0; half < 2; ++half) {
    const int g = (b + half * NB) * 256 + t;
    own[half] = __hip_atomic_load(&cnt[g], __ATOMIC_RELAXED, __HIP_MEMORY_SCOPE_AGENT);
    tmp[t] = own[half];
    __syncthreads();
    for (int s = 128; s > 0; s >>= 1) { if (t < s) tmp[t] += tmp[t + s]; __syncthreads(); }
    if (t == 0) bsum[b + half * NB] = tmp[0];
    __syncthreads();
  }
  gridbar(bar, 3 * NB);
  // phase 3: block 0 exclusive-scans bsum[512]
  if (b == 0) {
    const int o0 = bsum[t], o1 = bsum[t + 256];
    tmp[t] = o0; tmp[t + 256] = o1;
    __syncthreads();
    for (int off = 1; off < 256; off <<= 1) {
      const int a0 = (t >= off) ? tmp[t - off] : 0;
      const int a1 = (t >= off) ? tmp[256 + t - off] : 0;
      __syncthreads();
      tmp[t] += a0; tmp[256 + t] += a1;
      __syncthreads();
    }
    const int tot1 = tmp[255];
    bsum[t] = tmp[t] - o0;
    bsum[t + 256] = tmp[256 + t] + tot1 - o1;
  }
  gridbar(bar, 4 * NB);
  // phase 4: per-chunk exclusive scan -> baseA
#pragma unroll
  for (int half = 0; half < 2; ++half) {
    const int g = (b + half * NB) * 256 + t;
    const int bs = __hip_atomic_load(&bsum[b + half * NB], __ATOMIC_RELAXED, __HIP_MEMORY_SCOPE_AGENT);
    tmp[t] = own[half];
    __syncthreads();
    for (int off = 1; off < 256; off <<= 1) {
      const int a = (t >= off) ? tmp[t - off] : 0;
      __syncthreads();
      tmp[t] += a;
      __syncthreads();
    }
    baseA[g] = tmp[t] - own[half] + bs;
    __syncthreads();
  }
  if (b == 0 && t == 0) baseA[Nn] = Nn;  // E == N
  gridbar(bar, 5 * NB);
  // phase 5: scatter (cnt counts back down to zero)
#pragma unroll
  for (int half = 0; half < 2; ++half) {
    const int pos = baseA[row[half]] + atomicAdd(&cnt[row[half]], -1) - 1;
    rows_s[pos] = row[half];
    cols_s[pos] = col[half];
  }
}

// --- fused GEMM dispatch: blocks [0,nB1) -> GEMM1, [nB1,2*nB1) -> GEMM2 ----
// GEMM1: PRPC = [h|e] @ [[A|D];[B|C]]^T + b1  (O=512, K=512, ktSteps=16)
// GEMM2: VU   = h @ [V;U]^T + b2              (O=512, K=256, ktSteps=8)
__global__ __launch_bounds__(256) void gemm_fused(
    const unsigned short* __restrict__ h_t, const unsigned short* __restrict__ e_t,
    const unsigned short* __restrict__ W1h, const unsigned short* __restrict__ W1e,
    const unsigned short* __restrict__ W2t,
    const float* __restrict__ b1, const float* __restrict__ b2,
    unsigned short* __restrict__ PRPC, unsigned short* __restrict__ VU,
    int nB1) {
  __shared__ char lds[16384];
  const int g = blockIdx.x;
  const bool is2 = (g >= nB1);
  const int hw = is2 ? (g - nB1) : g;
  const unsigned short* Ah = h_t;
  const unsigned short* Ae = e_t;                       // unused for GEMM2
  const unsigned short* Bh = is2 ? W2t : W1h;
  const unsigned short* Be = is2 ? W2t : W1e;
  const float* bias = is2 ? b2 : b1;
  unsigned short* Cmat = is2 ? VU : PRPC;
  const int ktSteps = is2 ? 8 : 16;
  const int O = 512, nColBlk = 4;
  const int cpx = nB1 >> 3;
  const int bid = (hw % 8) * cpx + hw / 8;  // bijective XCD swizzle (nB1%8==0)
  const int colBlk = bid % nColBlk;
  const int rowBlk = bid / nColBlk;
  const int tid = threadIdx.x;
  const int w = tid >> 6, lane = tid & 63;
  const int wm = w >> 1, wn = w & 1;

  const size_t aTileOff = (size_t)(rowBlk * 8 + w * 2) * 8192 + lane * 16;
  const size_t bTileOff = (size_t)(colBlk * 8 + w * 2) * 8192 + lane * 16;
  char* ldsA0 = lds + (w * 2) * 1024;
  char* ldsA1 = lds + (w * 2 + 1) * 1024;
  char* ldsB0 = lds + 8192 + (w * 2) * 1024;
  char* ldsB1 = lds + 8192 + (w * 2 + 1) * 1024;

  f32x4 acc[4][4] = {};

  for (int kt = 0; kt < ktSteps; ++kt) {
    const char* Abase = (const char*)(kt < 8 ? Ah : Ae) + aTileOff + (size_t)(kt & 7) * 1024;
    const char* Bbase = (const char*)(kt < 8 ? Bh : Be) + bTileOff + (size_t)(kt & 7) * 1024;
    __builtin_amdgcn_global_load_lds((const __attribute__((address_space(1))) void*)Abase,
                                     (__attribute__((address_space(3))) void*)ldsA0, 16, 0, 0);
    __builtin_amdgcn_global_load_lds((const __attribute__((address_space(1))) void*)(Abase + 8192),
                                     (__attribute__((address_space(3))) void*)ldsA1, 16, 0, 0);
    __builtin_amdgcn_global_load_lds((const __attribute__((address_space(1))) void*)Bbase,
                                     (__attribute__((address_space(3))) void*)ldsB0, 16, 0, 0);
    __builtin_amdgcn_global_load_lds((const __attribute__((address_space(1))) void*)(Bbase + 8192),
                                     (__attribute__((address_space(3))) void*)ldsB1, 16, 0, 0);
    __syncthreads();
    bf16x8 a[4], b[4];
#pragma unroll
    for (int mi = 0; mi < 4; ++mi)
      a[mi] = *reinterpret_cast<const bf16x8*>(lds + (wm * 4 + mi) * 1024 + lane * 16);
#pragma unroll
    for (int ni = 0; ni < 4; ++ni)
      b[ni] = *reinterpret_cast<const bf16x8*>(lds + 8192 + (wn * 4 + ni) * 1024 + lane * 16);
#pragma unroll
    for (int mi = 0; mi < 4; ++mi)
#pragma unroll
      for (int ni = 0; ni < 4; ++ni)
        acc[mi][ni] = __builtin_amdgcn_mfma_f32_16x16x32_bf16(a[mi], b[ni], acc[mi][ni], 0, 0, 0);
    __syncthreads();
  }

  const int rb = rowBlk * 128 + wm * 64 + ((lane >> 4) << 2);
  const int cb = colBlk * 128 + wn * 64 + (lane & 15);
#pragma unroll
  for (int mi = 0; mi < 4; ++mi) {
#pragma unroll
    for (int ni = 0; ni < 4; ++ni) {
      const int coln = cb + ni * 16;
      const float bz = bias[coln];
      const size_t base = (size_t)(rb + mi * 16) * O + coln;
#pragma unroll
      for (int r = 0; r < 4; ++r)
        Cmat[base + (size_t)r * O] = (unsigned short)f2b(acc[mi][ni][r] + bz);
    }
  }
}

// --- BN batch stats over e_out[p] = PR[rows_s[p]] + PC[cols_s[p]] ----------
__global__ __launch_bounds__(256) void edge_stats(
    const unsigned short* __restrict__ PRPC,
    const int* __restrict__ rows_s, const int* __restrict__ cols_s,
    float* __restrict__ sums, float* __restrict__ sumsq) {
  __shared__ float red[8][256];
  const int c8 = threadIdx.x & 31;
  const int sub = threadIdx.x >> 5;
  float s[8], q[8];
#pragma unroll
  for (int j = 0; j < 8; ++j) { s[j] = 0.f; q[j] = 0.f; }
#pragma unroll 1
  for (int grp = 0; grp < 2; ++grp) {
    const int kb = blockIdx.x * 64 + grp * 32 + sub * 4;
    int r[4], cj[4];
#pragma unroll
    for (int u = 0; u < 4; ++u) { r[u] = rows_s[kb + u]; cj[u] = cols_s[kb + u]; }
    uint4 pr[4], pc[4];
#pragma unroll
    for (int u = 0; u < 4; ++u)
      pr[u] = *reinterpret_cast<const uint4*>(PRPC + (size_t)r[u] * 512 + c8 * 8);
#pragma unroll
    for (int u = 0; u < 4; ++u)
      pc[u] = *reinterpret_cast<const uint4*>(PRPC + (size_t)cj[u] * 512 + 256 + c8 * 8);
#pragma unroll
    for (int u = 0; u < 4; ++u) {
      const unsigned int rw[4] = {pr[u].x, pr[u].y, pr[u].z, pr[u].w};
      const unsigned int cw[4] = {pc[u].x, pc[u].y, pc[u].z, pc[u].w};
#pragma unroll
      for (int p4 = 0; p4 < 4; ++p4) {
        const float v0 = lof(rw[p4]) + lof(cw[p4]);
        const float v1 = hif(rw[p4]) + hif(cw[p4]);
        s[2 * p4] += v0;     q[2 * p4] += v0 * v0;
        s[2 * p4 + 1] += v1; q[2 * p4 + 1] += v1 * v1;
      }
    }
  }
#pragma unroll
  for (int j = 0; j < 8; ++j) red[sub][c8 * 8 + j] = s[j];
  __syncthreads();
  {
    const int c = threadIdx.x;
    float t = 0.f;
#pragma unroll
    for (int u2 = 0; u2 < 8; ++u2) t += red[u2][c];
    atomicAdd(sums + c, t);
  }
  __syncthreads();
#pragma unroll
  for (int j = 0; j < 8; ++j) red[sub][c8 * 8 + j] = q[j];
  __syncthreads();
  {
    const int c = threadIdx.x;
    float t = 0.f;
#pragma unroll
    for (int u2 = 0; u2 < 8; ++u2) t += red[u2][c];
    atomicAdd(sumsq + c, t);
  }
}

// --- fused: sig[i] = sigmoid(e[i] + sum_seg relu(sc*(PR[i]+PC[col])+sh))
//     accB[i] = bf16(sig); colsum += sig; Traw += sig * HV[col_orig[i]] -----
#define GCAP 1024
__global__ __launch_bounds__(256) void gather_sig_T(
    const float* __restrict__ e, const unsigned short* __restrict__ PRPC,
    const int* __restrict__ base, const int* __restrict__ cols_s,
    const int* __restrict__ ei, const int* __restrict__ modep,
    const unsigned short* __restrict__ VU,
    const float* __restrict__ sums, const float* __restrict__ sumsq,
    const float* __restrict__ gamma, const float* __restrict__ beta,
    unsigned short* __restrict__ accB, float* __restrict__ colsum,
    float* __restrict__ Traw, float invE, int Nn) {
  __shared__ float red[4][256];
  __shared__ int colsL[GCAP];
  __shared__ int baseL[65];
  const int lane = threadIdx.x & 63, w = threadIdx.x >> 6;
  const int n0 = blockIdx.x * 64;
  if (threadIdx.x < 65) baseL[threadIdx.x] = base[n0 + threadIdx.x];
  __syncthreads();
  const int bstart = baseL[0];
  const int bcount = baseL[64] - bstart;
  for (int qq = threadIdx.x; qq < bcount && qq < GCAP; qq += 256)
    colsL[qq] = cols_s[bstart + qq];
  const float4 sm = *reinterpret_cast<const float4*>(sums + lane * 4);
  const float4 sq = *reinterpret_cast<const float4*>(sumsq + lane * 4);
  const float4 gm = *reinterpret_cast<const float4*>(gamma + lane * 4);
  const float4 bt = *reinterpret_cast<const float4*>(beta + lane * 4);
  float4 sc, sh;
  {
    const float mx = sm.x * invE, my = sm.y * invE, mz = sm.z * invE, mw = sm.w * invE;
    sc.x = gm.x * rsqrtf(fmaxf(sq.x * invE - mx * mx, 0.f) + 1e-5f);
    sc.y = gm.y * rsqrtf(fmaxf(sq.y * invE - my * my, 0.f) + 1e-5f);
    sc.z = gm.z * rsqrtf(fmaxf(sq.z * invE - mz * mz, 0.f) + 1e-5f);
    sc.w = gm.w * rsqrtf(fmaxf(sq.w * invE - mw * mw, 0.f) + 1e-5f);
    sh.x = bt.x - mx * sc.x; sh.y = bt.y - my * sc.y;
    sh.z = bt.z - mz * sc.z; sh.w = bt.w - mw * sc.w;
  }
  __syncthreads();
  const int mode = *modep;
  float s0 = 0.f, s1 = 0.f, s2 = 0.f, s3 = 0.f;
  float t0 = 0.f, t1 = 0.f, t2 = 0.f, t3 = 0.f;
  const int i0 = n0 + w * 16;
  int p = baseL[w * 16];
  const int pendW = baseL[w * 16 + 16];
  uint2 pcn; pcn.x = 0; pcn.y = 0;
  if (p < pendW) {
    const int q0 = p - bstart;
    const int cj = (q0 < GCAP) ? colsL[q0] : cols_s[p];
    pcn = *reinterpret_cast<const uint2*>(PRPC + (size_t)cj * 512 + 256 + lane * 4);
  }
  float4 ev = *reinterpret_cast<const float4*>(e + (size_t)i0 * 256 + lane * 4);
  uint2 prv = *reinterpret_cast<const uint2*>(PRPC + (size_t)i0 * 512 + lane * 4);
#pragma unroll 1
  for (int it = 0; it < 16; ++it) {
    const int i = i0 + it;
    const int colT = mode ? ei[2 * (Nn + i)] : ei[Nn + i];
    const uint2 hv = *reinterpret_cast<const uint2*>(VU + (size_t)colT * 512 + lane * 4);
    float4 v = ev;
    const uint2 pr = prv;
    if (it + 1 < 16) {
      ev = *reinterpret_cast<const float4*>(e + (size_t)(i + 1) * 256 + lane * 4);
      prv = *reinterpret_cast<const uint2*>(PRPC + (size_t)(i + 1) * 512 + lane * 4);
    }
    const float pr0 = lof(pr.x), pr1 = hif(pr.x), pr2 = lof(pr.y), pr3 = hif(pr.y);
    const int pe = baseL[w * 16 + it + 1];
#pragma unroll 1
    while (p < pe) {
      const uint2 pc = pcn;
      if (p + 1 < pendW) {
        const int qn = p + 1 - bstart;
        const int cj = (qn < GCAP) ? colsL[qn] : cols_s[p + 1];
        pcn = *reinterpret_cast<const uint2*>(PRPC + (size_t)cj * 512 + 256 + lane * 4);
      }
      v.x += fmaxf(fmaf(sc.x, pr0 + lof(pc.x), sh.x), 0.f);
      v.y += fmaxf(fmaf(sc.y, pr1 + hif(pc.x), sh.y), 0.f);
      v.z += fmaxf(fmaf(sc.z, pr2 + lof(pc.y), sh.z), 0.f);
      v.w += fmaxf(fmaf(sc.w, pr3 + hif(pc.y), sh.w), 0.f);
      ++p;
    }
    v.x = 1.f / (1.f + __expf(-v.x));
    v.y = 1.f / (1.f + __expf(-v.y));
    v.z = 1.f / (1.f + __expf(-v.z));
    v.w = 1.f / (1.f + __expf(-v.w));
    uint2 ob;
    ob.x = f2b(v.x) | (f2b(v.y) << 16);
    ob.y = f2b(v.z) | (f2b(v.w) << 16);
    *reinterpret_cast<uint2*>(accB + (size_t)i * 256 + lane * 4) = ob;
    s0 += v.x; s1 += v.y; s2 += v.z; s3 += v.w;
    t0 += v.x * lof(hv.x); t1 += v.y * hif(hv.x);
    t2 += v.z * lof(hv.y); t3 += v.w * hif(hv.y);
  }
  red[w][lane * 4 + 0] = s0;
  red[w][lane * 4 + 1] = s1;
  red[w][lane * 4 + 2] = s2;
  red[w][lane * 4 + 3] = s3;
  __syncthreads();
  {
    const int c = threadIdx.x;
    atomicAdd(colsum + c, red[0][c] + red[1][c] + red[2][c] + red[3][c]);
  }
  __syncthreads();
  red[w][lane * 4 + 0] = t0;
  red[w][lane * 4 + 1] = t1;
  red[w][lane * 4 + 2] = t2;
  red[w][lane * 4 + 3] = t3;
  __syncthreads();
  {
    const int c = threadIdx.x;
    atomicAdd(Traw + c, red[0][c] + red[1][c] + red[2][c] + red[3][c]);
  }
}

// --- finalize: outE[i] = accB[i]*iv ; outH[i] = relu(HU[i] + iv*Traw) ------
__global__ __launch_bounds__(256) void finalize(
    const unsigned short* __restrict__ accB, const unsigned short* __restrict__ VU,
    const float* __restrict__ colsum, const float* __restrict__ Traw,
    float* __restrict__ outE, float* __restrict__ outH, int nChunks) {
  const int g = blockIdx.x * 256 + threadIdx.x;
  if (g >= nChunks) return;
  const int i = g >> 5, c8 = g & 31;
  const float4 cs0 = *reinterpret_cast<const float4*>(colsum + c8 * 8);
  const float4 cs1 = *reinterpret_cast<const float4*>(colsum + c8 * 8 + 4);
  const float4 tr0 = *reinterpret_cast<const float4*>(Traw + c8 * 8);
  const float4 tr1 = *reinterpret_cast<const float4*>(Traw + c8 * 8 + 4);
  float iv[8] = {1.f / (cs0.x + 1e-5f), 1.f / (cs0.y + 1e-5f),
                 1.f / (cs0.z + 1e-5f), 1.f / (cs0.w + 1e-5f),
                 1.f / (cs1.x + 1e-5f), 1.f / (cs1.y + 1e-5f),
                 1.f / (cs1.z + 1e-5f), 1.f / (cs1.w + 1e-5f)};
  float tt[8] = {tr0.x * iv[0], tr0.y * iv[1], tr0.z * iv[2], tr0.w * iv[3],
                 tr1.x * iv[4], tr1.y * iv[5], tr1.z * iv[6], tr1.w * iv[7]};
  const uint4 sb = *reinterpret_cast<const uint4*>(accB + (size_t)i * 256 + c8 * 8);
  const unsigned int sw[4] = {sb.x, sb.y, sb.z, sb.w};
  float4 e0, e1;
  e0.x = lof(sw[0]) * iv[0]; e0.y = hif(sw[0]) * iv[1];
  e0.z = lof(sw[1]) * iv[2]; e0.w = hif(sw[1]) * iv[3];
  e1.x = lof(sw[2]) * iv[4]; e1.y = hif(sw[2]) * iv[5];
  e1.z = lof(sw[3]) * iv[6]; e1.w = hif(sw[3]) * iv[7];
  float4* qe = reinterpret_cast<float4*>(outE + (size_t)i * 256 + c8 * 8);
  qe[0] = e0; qe[1] = e1;
  const uint4 hu = *reinterpret_cast<const uint4*>(VU + (size_t)i * 512 + 256 + c8 * 8);
  float4 o0, o1;
  o0.x = fmaxf(lof(hu.x) + tt[0], 0.f);
  o0.y = fmaxf(hif(hu.x) + tt[1], 0.f);
  o0.z = fmaxf(lof(hu.y) + tt[2], 0.f);
  o0.w = fmaxf(hif(hu.y) + tt[3], 0.f);
  o1.x = fmaxf(lof(hu.z) + tt[4], 0.f);
  o1.y = fmaxf(hif(hu.z) + tt[5], 0.f);
  o1.z = fmaxf(lof(hu.w) + tt[6], 0.f);
  o1.w = fmaxf(hif(hu.w) + tt[7], 0.f);
  float4* qh = reinterpret_cast<float4*>(outH + (size_t)i * 256 + c8 * 8);
  qh[0] = o0; qh[1] = o1;
}

extern "C" void kernel_launch(void* const* d_in, const int* in_sizes, int n_in,
                              void* d_out, int out_size, void* d_ws, size_t ws_size,
                              hipStream_t stream) {
  const float* h     = (const float*)d_in[0];
  const int*   ei    = (const int*)d_in[1];
  const float* e     = (const float*)d_in[2];
  const float* Aw    = (const float*)d_in[3];
  const float* Ab    = (const float*)d_in[4];
  const float* Bw    = (const float*)d_in[5];
  const float* Bb    = (const float*)d_in[6];
  const float* Cw    = (const float*)d_in[7];
  const float* Cb    = (const float*)d_in[8];
  const float* Dw    = (const float*)d_in[9];
  const float* Db    = (const float*)d_in[10];
  const float* gamma = (const float*)d_in[11];
  const float* beta  = (const float*)d_in[12];
  const float* Uw    = (const float*)d_in[13];
  const float* Ub    = (const float*)d_in[14];
  const float* Vw    = (const float*)d_in[15];
  const float* Vb    = (const float*)d_in[16];
  const int N = in_sizes[0] / 256;  // 131072

  char* ws = (char*)d_ws;
  unsigned short* W1h = (unsigned short*)(ws + 0x0);       // [A;B] tiled, 256 KiB
  unsigned short* W1e = (unsigned short*)(ws + 0x40000);   // [D;C] tiled, 256 KiB
  unsigned short* W2t = (unsigned short*)(ws + 0x80000);   // [V;U] tiled, 256 KiB
  float* b1     = (float*)(ws + 0xC0000);
  float* b2     = (float*)(ws + 0xC0800);
  float* sums   = (float*)(ws + 0xC1000);
  float* sumsq  = (float*)(ws + 0xC1400);
  float* colsum = (float*)(ws + 0xC1800);
  float* Traw   = (float*)(ws + 0xC1C00);
  int*   mode   = (int*)(ws + 0xC2C00);
  int*   bar    = (int*)(ws + 0xC2D00);
  unsigned short* h_t  = (unsigned short*)(ws + 0x100000);   // 64 MiB
  unsigned short* e_t  = (unsigned short*)(ws + 0x4100000);  // 64 MiB
  unsigned short* PRPC = (unsigned short*)(ws + 0x8100000);  // 128 MiB
  unsigned short* VU   = (unsigned short*)(ws + 0x10100000); // 128 MiB
  unsigned short* accB = (unsigned short*)(ws + 0x100000);   // overlays h_t (dead after GEMMs)
  int* cnt    = (int*)(ws + 0x18100000);
  int* baseA  = (int*)(ws + 0x18180000);
  int* rows_s = (int*)(ws + 0x18210000);
  int* cols_s = (int*)(ws + 0x18290000);
  int* bsum   = (int*)(ws + 0x18310000);

  float* outH = (float*)d_out;
  float* outE = outH + (size_t)N * 256;

  prep_weights<<<192, 256, 0, stream>>>(Aw, Bw, Dw, Cw, Vw, Uw, W1h, W1e, W2t,
                                        Ab, Db, Bb, Cb, Vb, Ub, b1, b2,
                                        sums, sumsq, colsum, Traw, ei, mode, bar);
  coop_sort<<<256, 256, 0, stream>>>(ei, mode, cnt, bsum, baseA, rows_s, cols_s, bar, N);

  const int nChunks = N * 32;
  prep_he<<<2 * nChunks / 256, 256, 0, stream>>>(h, h_t, e, e_t, nChunks);
  const int nB1 = (N / 128) * 4;  // 4096 blocks per GEMM
  gemm_fused<<<2 * nB1, 256, 0, stream>>>(h_t, e_t, W1h, W1e, W2t, b1, b2, PRPC, VU, nB1);

  edge_stats<<<N / 64, 256, 0, stream>>>(PRPC, rows_s, cols_s, sums, sumsq);
  gather_sig_T<<<N / 64, 256, 0, stream>>>(e, PRPC, baseA, cols_s, ei, mode, VU,
                                           sums, sumsq, gamma, beta,
                                           accB, colsum, Traw, 1.0f / (float)N, N);
  finalize<<<nChunks / 256, 256, 0, stream>>>(accB, VU, colsum, Traw, outE, outH, nChunks);
}

// Round 8
// 582.683 us; speedup vs baseline: 1.0822x; 1.0822x over previous
//
#include <hip/hip_runtime.h>
#include <hip/hip_bf16.h>

// ---------------------------------------------------------------------------
// GatedNetwork: N = 131072 nodes == edges, C = 256 channels.
// Factorization: e_out[k] = PR[row[k]] + PC[col[k]],
//   PR = h@A^T + e@D^T + (Ab+Db),  PC = h@B^T + e@C^T + (Bb+Cb)
// Pipeline (13 dispatches, R6 structure):
//   prep_weights (weights->tiled bf16, bias pack, idx-mode, zero stats)
//   memset(cnt) | sort: hist, scan1, scan2, scan3, scatter
//   prep_he | GEMM1 PRPC | GEMM2 VU   (2-phase double-buffered LDS)
//   edge_stats | gather_sig_T | finalize
// ---------------------------------------------------------------------------

typedef __attribute__((ext_vector_type(8))) short bf16x8;
typedef __attribute__((ext_vector_type(4))) float f32x4;

__device__ __forceinline__ float b2f(unsigned int lo16) {
  union { unsigned int u; float f; } c; c.u = lo16 << 16; return c.f;
}
__device__ __forceinline__ float lof(unsigned int u) { return b2f(u & 0xffffu); }
__device__ __forceinline__ float hif(unsigned int u) { return b2f(u >> 16); }
__device__ __forceinline__ unsigned int f2b(float f) {  // RNE f32->bf16
  union { float f; unsigned int u; } c; c.f = f;
  unsigned int u = c.u;
  u += 0x7fffu + ((u >> 16) & 1u);
  return u >> 16;
}

// --- prep: f32 row-major [M][256] -> bf16 tiled [M/16][32][16][8] ----------
__device__ __forceinline__ void prep_chunk(const float* __restrict__ src,
                                           unsigned short* __restrict__ dst, int g) {
  int mtile = g >> 9;
  int rem = g & 511;
  int r = rem >> 5, k8 = rem & 31;
  const float4* s = reinterpret_cast<const float4*>(src + (((size_t)mtile * 16 + r) << 8) + k8 * 8);
  float4 v0 = s[0], v1 = s[1];
  uint4 o;
  o.x = f2b(v0.x) | (f2b(v0.y) << 16);
  o.y = f2b(v0.z) | (f2b(v0.w) << 16);
  o.z = f2b(v1.x) | (f2b(v1.y) << 16);
  o.w = f2b(v1.z) | (f2b(v1.w) << 16);
  *reinterpret_cast<uint4*>(dst + ((size_t)mtile * 512 + k8 * 16 + r) * 8) = o;
}

__global__ __launch_bounds__(256) void prep_he(const float* __restrict__ h,
                                               unsigned short* __restrict__ h_t,
                                               const float* __restrict__ e,
                                               unsigned short* __restrict__ e_t,
                                               int nChunksEach) {
  int g = blockIdx.x * 256 + threadIdx.x;
  if (g < nChunksEach) prep_chunk(h, h_t, g);
  else if (g < 2 * nChunksEach) prep_chunk(e, e_t, g - nChunksEach);
}

// weights -> tiled bf16; block 0 also: bias pack, idx-mode, zero stats
__global__ __launch_bounds__(256) void prep_weights(
    const float* __restrict__ s0, const float* __restrict__ s1,
    const float* __restrict__ s2, const float* __restrict__ s3,
    const float* __restrict__ s4, const float* __restrict__ s5,
    unsigned short* __restrict__ W1h, unsigned short* __restrict__ W1e,
    unsigned short* __restrict__ W2t,
    const float* __restrict__ Ab, const float* __restrict__ Db,
    const float* __restrict__ Bb, const float* __restrict__ Cb,
    const float* __restrict__ Vb, const float* __restrict__ Ub,
    float* __restrict__ b1, float* __restrict__ b2,
    float* __restrict__ sums, float* __restrict__ sumsq,
    float* __restrict__ colsum, float* __restrict__ Traw,
    const int* __restrict__ ei, int* __restrict__ mode) {
  int g = blockIdx.x * 256 + threadIdx.x;
  if (blockIdx.x == 0) {
    const int t = threadIdx.x;
    b1[t] = Ab[t] + Db[t];
    b1[256 + t] = Bb[t] + Cb[t];
    b2[t] = Vb[t];
    b2[256 + t] = Ub[t];
    sums[t] = 0.f; sumsq[t] = 0.f; colsum[t] = 0.f; Traw[t] = 0.f;
    if (t == 0) {
      int m = 0;
#pragma unroll
      for (int i = 1; i < 64; i += 2) m |= ei[i];
      *mode = (m == 0) ? 1 : 0;
    }
  }
  int sel = g >> 13;
  int gg = g & 8191;
  const float* src; unsigned short* dst;
  switch (sel) {
    case 0: src = s0; dst = W1h; break;           // A
    case 1: src = s1; dst = W1h + 65536; break;   // B
    case 2: src = s2; dst = W1e; break;           // D
    case 3: src = s3; dst = W1e + 65536; break;   // C
    case 4: src = s4; dst = W2t; break;           // V
    default: src = s5; dst = W2t + 65536; break;  // U
  }
  prep_chunk(src, dst, gg);
}

// --- GEMM (two K-sources), 2-phase double-buffered LDS ---------------------
// kt<8 reads (Ah,Bh), kt>=8 reads (Ae,Be). ktSteps=8 -> single-source K=256.
// Schedule per pair: stage(kt+1,buf1); compute(buf0); bar; stage(kt+2,buf0);
// compute(buf1); bar.  Next-tile loads are in flight during ds_read+MFMA.
__global__ __launch_bounds__(256) void gemm_bt2(
    const unsigned short* __restrict__ Ah, const unsigned short* __restrict__ Ae,
    const unsigned short* __restrict__ Bh, const unsigned short* __restrict__ Be,
    const float* __restrict__ bias, unsigned short* __restrict__ Cmat,
    int O, int nColBlk, int ktSteps, int nBlk) {
  __shared__ char lds[32768];  // A0 [0,8K) A1 [8K,16K) B0 [16K,24K) B1 [24K,32K)
  const int cpx = nBlk >> 3;
  const int hw = blockIdx.x;
  const int bid = (hw % 8) * cpx + hw / 8;  // bijective XCD swizzle (nBlk%8==0)
  const int colBlk = bid % nColBlk;
  const int rowBlk = bid / nColBlk;
  const int tid = threadIdx.x;
  const int w = tid >> 6, lane = tid & 63;
  const int wm = w >> 1, wn = w & 1;

  const size_t aTileOff = (size_t)(rowBlk * 8 + w * 2) * 8192 + lane * 16;
  const size_t bTileOff = (size_t)(colBlk * 8 + w * 2) * 8192 + lane * 16;
  const int wOff0 = (w * 2) * 1024;
  const int wOff1 = (w * 2 + 1) * 1024;

  f32x4 acc[4][4] = {};

  auto stage = [&](int kt, char* bufA, char* bufB) {
    const char* Ab_ = (const char*)(kt < 8 ? Ah : Ae) + aTileOff + (size_t)(kt & 7) * 1024;
    const char* Bb_ = (const char*)(kt < 8 ? Bh : Be) + bTileOff + (size_t)(kt & 7) * 1024;
    __builtin_amdgcn_global_load_lds((const __attribute__((address_space(1))) void*)Ab_,
                                     (__attribute__((address_space(3))) void*)(bufA + wOff0), 16, 0, 0);
    __builtin_amdgcn_global_load_lds((const __attribute__((address_space(1))) void*)(Ab_ + 8192),
                                     (__attribute__((address_space(3))) void*)(bufA + wOff1), 16, 0, 0);
    __builtin_amdgcn_global_load_lds((const __attribute__((address_space(1))) void*)Bb_,
                                     (__attribute__((address_space(3))) void*)(bufB + wOff0), 16, 0, 0);
    __builtin_amdgcn_global_load_lds((const __attribute__((address_space(1))) void*)(Bb_ + 8192),
                                     (__attribute__((address_space(3))) void*)(bufB + wOff1), 16, 0, 0);
  };
  auto compute = [&](const char* bufA, const char* bufB) {
    bf16x8 a[4], b[4];
#pragma unroll
    for (int mi = 0; mi < 4; ++mi)
      a[mi] = *reinterpret_cast<const bf16x8*>(bufA + (wm * 4 + mi) * 1024 + lane * 16);
#pragma unroll
    for (int ni = 0; ni < 4; ++ni)
      b[ni] = *reinterpret_cast<const bf16x8*>(bufB + (wn * 4 + ni) * 1024 + lane * 16);
#pragma unroll
    for (int mi = 0; mi < 4; ++mi)
#pragma unroll
      for (int ni = 0; ni < 4; ++ni)
        acc[mi][ni] = __builtin_amdgcn_mfma_f32_16x16x32_bf16(a[mi], b[ni], acc[mi][ni], 0, 0, 0);
  };

  char* A0 = lds;          char* A1 = lds + 8192;
  char* B0 = lds + 16384;  char* B1 = lds + 24576;

  stage(0, A0, B0);
  __syncthreads();                       // prologue drain: buf0 ready
#pragma unroll 1
  for (int kt = 0; kt < ktSteps; kt += 2) {
    stage(kt + 1, A1, B1);               // in flight during compute(buf0)
    compute(A0, B0);
    __syncthreads();                     // drains stage(kt+1); all read buf0
    if (kt + 2 < ktSteps) stage(kt + 2, A0, B0);
    compute(A1, B1);
    __syncthreads();                     // drains stage(kt+2); all read buf1
  }

  const int rb = rowBlk * 128 + wm * 64 + ((lane >> 4) << 2);
  const int cb = colBlk * 128 + wn * 64 + (lane & 15);
#pragma unroll
  for (int mi = 0; mi < 4; ++mi) {
#pragma unroll
    for (int ni = 0; ni < 4; ++ni) {
      const int coln = cb + ni * 16;
      const float bz = bias[coln];
      const size_t base = (size_t)(rb + mi * 16) * O + coln;
#pragma unroll
      for (int r = 0; r < 4; ++r)
        Cmat[base + (size_t)r * O] = (unsigned short)f2b(acc[mi][ni][r] + bz);
    }
  }
}

// --- BN batch stats over e_out[p] = PR[rows_s[p]] + PC[cols_s[p]] ----------
__global__ __launch_bounds__(256) void edge_stats(
    const unsigned short* __restrict__ PRPC,
    const int* __restrict__ rows_s, const int* __restrict__ cols_s,
    float* __restrict__ sums, float* __restrict__ sumsq) {
  __shared__ float red[8][256];
  const int c8 = threadIdx.x & 31;
  const int sub = threadIdx.x >> 5;
  float s[8], q[8];
#pragma unroll
  for (int j = 0; j < 8; ++j) { s[j] = 0.f; q[j] = 0.f; }
#pragma unroll 1
  for (int grp = 0; grp < 2; ++grp) {
    const int kb = blockIdx.x * 64 + grp * 32 + sub * 4;
    int r[4], cj[4];
#pragma unroll
    for (int u = 0; u < 4; ++u) { r[u] = rows_s[kb + u]; cj[u] = cols_s[kb + u]; }
    uint4 pr[4], pc[4];
#pragma unroll
    for (int u = 0; u < 4; ++u)
      pr[u] = *reinterpret_cast<const uint4*>(PRPC + (size_t)r[u] * 512 + c8 * 8);
#pragma unroll
    for (int u = 0; u < 4; ++u)
      pc[u] = *reinterpret_cast<const uint4*>(PRPC + (size_t)cj[u] * 512 + 256 + c8 * 8);
#pragma unroll
    for (int u = 0; u < 4; ++u) {
      const unsigned int rw[4] = {pr[u].x, pr[u].y, pr[u].z, pr[u].w};
      const unsigned int cw[4] = {pc[u].x, pc[u].y, pc[u].z, pc[u].w};
#pragma unroll
      for (int p4 = 0; p4 < 4; ++p4) {
        const float v0 = lof(rw[p4]) + lof(cw[p4]);
        const float v1 = hif(rw[p4]) + hif(cw[p4]);
        s[2 * p4] += v0;     q[2 * p4] += v0 * v0;
        s[2 * p4 + 1] += v1; q[2 * p4 + 1] += v1 * v1;
      }
    }
  }
#pragma unroll
  for (int j = 0; j < 8; ++j) red[sub][c8 * 8 + j] = s[j];
  __syncthreads();
  {
    const int c = threadIdx.x;
    float t = 0.f;
#pragma unroll
    for (int u2 = 0; u2 < 8; ++u2) t += red[u2][c];
    atomicAdd(sums + c, t);
  }
  __syncthreads();
#pragma unroll
  for (int j = 0; j < 8; ++j) red[sub][c8 * 8 + j] = q[j];
  __syncthreads();
  {
    const int c = threadIdx.x;
    float t = 0.f;
#pragma unroll
    for (int u2 = 0; u2 < 8; ++u2) t += red[u2][c];
    atomicAdd(sumsq + c, t);
  }
}

// --- counting sort of edges by row -----------------------------------------
__global__ __launch_bounds__(256) void hist_rows(const int* __restrict__ ei,
                                                 const int* __restrict__ modep,
                                                 int* __restrict__ cnt, int Nn) {
  const int k = blockIdx.x * 256 + threadIdx.x;
  if (k >= Nn) return;
  const int row = (*modep) ? ei[2 * k] : ei[k];
  atomicAdd(&cnt[row], 1);
}

__global__ __launch_bounds__(256) void scan1(const int* __restrict__ cnt,
                                             int* __restrict__ bsum) {
  __shared__ int red[256];
  const int t = threadIdx.x;
  red[t] = cnt[blockIdx.x * 256 + t];
  __syncthreads();
#pragma unroll
  for (int s = 128; s > 0; s >>= 1) {
    if (t < s) red[t] += red[t + s];
    __syncthreads();
  }
  if (t == 0) bsum[blockIdx.x] = red[0];
}

__global__ __launch_bounds__(512) void scan2(int* __restrict__ bsum, int nb) {
  __shared__ int tmp[512];
  const int t = threadIdx.x;
  const int own = (t < nb) ? bsum[t] : 0;
  tmp[t] = own;
  __syncthreads();
  for (int off = 1; off < 512; off <<= 1) {
    int v = (t >= off) ? tmp[t - off] : 0;
    __syncthreads();
    tmp[t] += v;
    __syncthreads();
  }
  if (t < nb) bsum[t] = tmp[t] - own;  // exclusive
}

__global__ __launch_bounds__(256) void scan3(const int* __restrict__ cnt,
                                             const int* __restrict__ bsum,
                                             int* __restrict__ base, int Nn) {
  __shared__ int tmp[256];
  const int t = threadIdx.x;
  const int gid = blockIdx.x * 256 + t;
  const int own = cnt[gid];
  tmp[t] = own;
  __syncthreads();
  for (int off = 1; off < 256; off <<= 1) {
    int v = (t >= off) ? tmp[t - off] : 0;
    __syncthreads();
    tmp[t] += v;
    __syncthreads();
  }
  base[gid] = tmp[t] - own + bsum[blockIdx.x];
  if (gid == 0) base[Nn] = Nn;  // E == N
}

__global__ __launch_bounds__(256) void scatter_eids(const int* __restrict__ ei,
                                                    const int* __restrict__ modep,
                                                    const int* __restrict__ base,
                                                    int* __restrict__ cnt,
                                                    int* __restrict__ rows_s,
                                                    int* __restrict__ cols_s, int Nn) {
  const int k = blockIdx.x * 256 + threadIdx.x;
  if (k >= Nn) return;
  int row, col;
  if (*modep) { row = ei[2 * k]; col = ei[2 * (Nn + k)]; }
  else        { row = ei[k];     col = ei[Nn + k]; }
  const int pos = base[row] + atomicAdd(&cnt[row], -1) - 1;
  rows_s[pos] = row;
  cols_s[pos] = col;
}

// --- fused: sig[i] = sigmoid(e[i] + sum_seg relu(sc*(PR[i]+PC[col])+sh))
//     accB[i] = bf16(sig); colsum += sig; Traw += sig * HV[col_orig[i]] -----
#define GCAP 1024
__global__ __launch_bounds__(256) void gather_sig_T(
    const float* __restrict__ e, const unsigned short* __restrict__ PRPC,
    const int* __restrict__ base, const int* __restrict__ cols_s,
    const int* __restrict__ ei, const int* __restrict__ modep,
    const unsigned short* __restrict__ VU,
    const float* __restrict__ sums, const float* __restrict__ sumsq,
    const float* __restrict__ gamma, const float* __restrict__ beta,
    unsigned short* __restrict__ accB, float* __restrict__ colsum,
    float* __restrict__ Traw, float invE, int Nn) {
  __shared__ float red[4][256];
  __shared__ int colsL[GCAP];
  __shared__ int baseL[65];
  const int lane = threadIdx.x & 63, w = threadIdx.x >> 6;
  const int n0 = blockIdx.x * 64;
  if (threadIdx.x < 65) baseL[threadIdx.x] = base[n0 + threadIdx.x];
  __syncthreads();
  const int bstart = baseL[0];
  const int bcount = baseL[64] - bstart;
  for (int qq = threadIdx.x; qq < bcount && qq < GCAP; qq += 256)
    colsL[qq] = cols_s[bstart + qq];
  const float4 sm = *reinterpret_cast<const float4*>(sums + lane * 4);
  const float4 sq = *reinterpret_cast<const float4*>(sumsq + lane * 4);
  const float4 gm = *reinterpret_cast<const float4*>(gamma + lane * 4);
  const float4 bt = *reinterpret_cast<const float4*>(beta + lane * 4);
  float4 sc, sh;
  {
    const float mx = sm.x * invE, my = sm.y * invE, mz = sm.z * invE, mw = sm.w * invE;
    sc.x = gm.x * rsqrtf(fmaxf(sq.x * invE - mx * mx, 0.f) + 1e-5f);
    sc.y = gm.y * rsqrtf(fmaxf(sq.y * invE - my * my, 0.f) + 1e-5f);
    sc.z = gm.z * rsqrtf(fmaxf(sq.z * invE - mz * mz, 0.f) + 1e-5f);
    sc.w = gm.w * rsqrtf(fmaxf(sq.w * invE - mw * mw, 0.f) + 1e-5f);
    sh.x = bt.x - mx * sc.x; sh.y = bt.y - my * sc.y;
    sh.z = bt.z - mz * sc.z; sh.w = bt.w - mw * sc.w;
  }
  __syncthreads();
  const int mode = *modep;
  float s0 = 0.f, s1 = 0.f, s2 = 0.f, s3 = 0.f;
  float t0 = 0.f, t1 = 0.f, t2 = 0.f, t3 = 0.f;
  const int i0 = n0 + w * 16;
  int p = baseL[w * 16];
  const int pendW = baseL[w * 16 + 16];
  uint2 pcn; pcn.x = 0; pcn.y = 0;
  if (p < pendW) {
    const int q0 = p - bstart;
    const int cj = (q0 < GCAP) ? colsL[q0] : cols_s[p];
    pcn = *reinterpret_cast<const uint2*>(PRPC + (size_t)cj * 512 + 256 + lane * 4);
  }
  float4 ev = *reinterpret_cast<const float4*>(e + (size_t)i0 * 256 + lane * 4);
  uint2 prv = *reinterpret_cast<const uint2*>(PRPC + (size_t)i0 * 512 + lane * 4);
#pragma unroll 1
  for (int it = 0; it < 16; ++it) {
    const int i = i0 + it;
    const int colT = mode ? ei[2 * (Nn + i)] : ei[Nn + i];
    const uint2 hv = *reinterpret_cast<const uint2*>(VU + (size_t)colT * 512 + lane * 4);
    float4 v = ev;
    const uint2 pr = prv;
    if (it + 1 < 16) {
      ev = *reinterpret_cast<const float4*>(e + (size_t)(i + 1) * 256 + lane * 4);
      prv = *reinterpret_cast<const uint2*>(PRPC + (size_t)(i + 1) * 512 + lane * 4);
    }
    const float pr0 = lof(pr.x), pr1 = hif(pr.x), pr2 = lof(pr.y), pr3 = hif(pr.y);
    const int pe = baseL[w * 16 + it + 1];
#pragma unroll 1
    while (p < pe) {
      const uint2 pc = pcn;
      if (p + 1 < pendW) {
        const int qn = p + 1 - bstart;
        const int cj = (qn < GCAP) ? colsL[qn] : cols_s[p + 1];
        pcn = *reinterpret_cast<const uint2*>(PRPC + (size_t)cj * 512 + 256 + lane * 4);
      }
      v.x += fmaxf(fmaf(sc.x, pr0 + lof(pc.x), sh.x), 0.f);
      v.y += fmaxf(fmaf(sc.y, pr1 + hif(pc.x), sh.y), 0.f);
      v.z += fmaxf(fmaf(sc.z, pr2 + lof(pc.y), sh.z), 0.f);
      v.w += fmaxf(fmaf(sc.w, pr3 + hif(pc.y), sh.w), 0.f);
      ++p;
    }
    v.x = 1.f / (1.f + __expf(-v.x));
    v.y = 1.f / (1.f + __expf(-v.y));
    v.z = 1.f / (1.f + __expf(-v.z));
    v.w = 1.f / (1.f + __expf(-v.w));
    uint2 ob;
    ob.x = f2b(v.x) | (f2b(v.y) << 16);
    ob.y = f2b(v.z) | (f2b(v.w) << 16);
    *reinterpret_cast<uint2*>(accB + (size_t)i * 256 + lane * 4) = ob;
    s0 += v.x; s1 += v.y; s2 += v.z; s3 += v.w;
    t0 += v.x * lof(hv.x); t1 += v.y * hif(hv.x);
    t2 += v.z * lof(hv.y); t3 += v.w * hif(hv.y);
  }
  red[w][lane * 4 + 0] = s0;
  red[w][lane * 4 + 1] = s1;
  red[w][lane * 4 + 2] = s2;
  red[w][lane * 4 + 3] = s3;
  __syncthreads();
  {
    const int c = threadIdx.x;
    atomicAdd(colsum + c, red[0][c] + red[1][c] + red[2][c] + red[3][c]);
  }
  __syncthreads();
  red[w][lane * 4 + 0] = t0;
  red[w][lane * 4 + 1] = t1;
  red[w][lane * 4 + 2] = t2;
  red[w][lane * 4 + 3] = t3;
  __syncthreads();
  {
    const int c = threadIdx.x;
    atomicAdd(Traw + c, red[0][c] + red[1][c] + red[2][c] + red[3][c]);
  }
}

// --- finalize: outE[i] = accB[i]*iv ; outH[i] = relu(HU[i] + iv*Traw) ------
__global__ __launch_bounds__(256) void finalize(
    const unsigned short* __restrict__ accB, const unsigned short* __restrict__ VU,
    const float* __restrict__ colsum, const float* __restrict__ Traw,
    float* __restrict__ outE, float* __restrict__ outH, int nChunks) {
  const int g = blockIdx.x * 256 + threadIdx.x;
  if (g >= nChunks) return;
  const int i = g >> 5, c8 = g & 31;
  const float4 cs0 = *reinterpret_cast<const float4*>(colsum + c8 * 8);
  const float4 cs1 = *reinterpret_cast<const float4*>(colsum + c8 * 8 + 4);
  const float4 tr0 = *reinterpret_cast<const float4*>(Traw + c8 * 8);
  const float4 tr1 = *reinterpret_cast<const float4*>(Traw + c8 * 8 + 4);
  float iv[8] = {1.f / (cs0.x + 1e-5f), 1.f / (cs0.y + 1e-5f),
                 1.f / (cs0.z + 1e-5f), 1.f / (cs0.w + 1e-5f),
                 1.f / (cs1.x + 1e-5f), 1.f / (cs1.y + 1e-5f),
                 1.f / (cs1.z + 1e-5f), 1.f / (cs1.w + 1e-5f)};
  float tt[8] = {tr0.x * iv[0], tr0.y * iv[1], tr0.z * iv[2], tr0.w * iv[3],
                 tr1.x * iv[4], tr1.y * iv[5], tr1.z * iv[6], tr1.w * iv[7]};
  const uint4 sb = *reinterpret_cast<const uint4*>(accB + (size_t)i * 256 + c8 * 8);
  const unsigned int sw[4] = {sb.x, sb.y, sb.z, sb.w};
  float4 e0, e1;
  e0.x = lof(sw[0]) * iv[0]; e0.y = hif(sw[0]) * iv[1];
  e0.z = lof(sw[1]) * iv[2]; e0.w = hif(sw[1]) * iv[3];
  e1.x = lof(sw[2]) * iv[4]; e1.y = hif(sw[2]) * iv[5];
  e1.z = lof(sw[3]) * iv[6]; e1.w = hif(sw[3]) * iv[7];
  float4* qe = reinterpret_cast<float4*>(outE + (size_t)i * 256 + c8 * 8);
  qe[0] = e0; qe[1] = e1;
  const uint4 hu = *reinterpret_cast<const uint4*>(VU + (size_t)i * 512 + 256 + c8 * 8);
  float4 o0, o1;
  o0.x = fmaxf(lof(hu.x) + tt[0], 0.f);
  o0.y = fmaxf(hif(hu.x) + tt[1], 0.f);
  o0.z = fmaxf(lof(hu.y) + tt[2], 0.f);
  o0.w = fmaxf(hif(hu.y) + tt[3], 0.f);
  o1.x = fmaxf(lof(hu.z) + tt[4], 0.f);
  o1.y = fmaxf(hif(hu.z) + tt[5], 0.f);
  o1.z = fmaxf(lof(hu.w) + tt[6], 0.f);
  o1.w = fmaxf(hif(hu.w) + tt[7], 0.f);
  float4* qh = reinterpret_cast<float4*>(outH + (size_t)i * 256 + c8 * 8);
  qh[0] = o0; qh[1] = o1;
}

extern "C" void kernel_launch(void* const* d_in, const int* in_sizes, int n_in,
                              void* d_out, int out_size, void* d_ws, size_t ws_size,
                              hipStream_t stream) {
  const float* h     = (const float*)d_in[0];
  const int*   ei    = (const int*)d_in[1];
  const float* e     = (const float*)d_in[2];
  const float* Aw    = (const float*)d_in[3];
  const float* Ab    = (const float*)d_in[4];
  const float* Bw    = (const float*)d_in[5];
  const float* Bb    = (const float*)d_in[6];
  const float* Cw    = (const float*)d_in[7];
  const float* Cb    = (const float*)d_in[8];
  const float* Dw    = (const float*)d_in[9];
  const float* Db    = (const float*)d_in[10];
  const float* gamma = (const float*)d_in[11];
  const float* beta  = (const float*)d_in[12];
  const float* Uw    = (const float*)d_in[13];
  const float* Ub    = (const float*)d_in[14];
  const float* Vw    = (const float*)d_in[15];
  const float* Vb    = (const float*)d_in[16];
  const int N = in_sizes[0] / 256;  // 131072

  char* ws = (char*)d_ws;
  unsigned short* W1h = (unsigned short*)(ws + 0x0);       // [A;B] tiled, 256 KiB
  unsigned short* W1e = (unsigned short*)(ws + 0x40000);   // [D;C] tiled, 256 KiB
  unsigned short* W2t = (unsigned short*)(ws + 0x80000);   // [V;U] tiled, 256 KiB
  float* b1     = (float*)(ws + 0xC0000);
  float* b2     = (float*)(ws + 0xC0800);
  float* sums   = (float*)(ws + 0xC1000);
  float* sumsq  = (float*)(ws + 0xC1400);
  float* colsum = (float*)(ws + 0xC1800);
  float* Traw   = (float*)(ws + 0xC1C00);
  int*   mode   = (int*)(ws + 0xC2C00);
  unsigned short* h_t  = (unsigned short*)(ws + 0x100000);   // 64 MiB
  unsigned short* e_t  = (unsigned short*)(ws + 0x4100000);  // 64 MiB
  unsigned short* PRPC = (unsigned short*)(ws + 0x8100000);  // 128 MiB
  unsigned short* VU   = (unsigned short*)(ws + 0x10100000); // 128 MiB
  unsigned short* accB = (unsigned short*)(ws + 0x100000);   // overlays h_t (dead after GEMMs)
  int* cnt    = (int*)(ws + 0x18100000);
  int* baseA  = (int*)(ws + 0x18180000);
  int* rows_s = (int*)(ws + 0x18210000);
  int* cols_s = (int*)(ws + 0x18290000);
  int* bsum   = (int*)(ws + 0x18310000);

  float* outH = (float*)d_out;
  float* outE = outH + (size_t)N * 256;

  hipMemsetAsync(cnt, 0, (size_t)N * 4, stream);
  prep_weights<<<192, 256, 0, stream>>>(Aw, Bw, Dw, Cw, Vw, Uw, W1h, W1e, W2t,
                                        Ab, Db, Bb, Cb, Vb, Ub, b1, b2,
                                        sums, sumsq, colsum, Traw, ei, mode);

  // counting sort of edges by row
  hist_rows<<<N / 256, 256, 0, stream>>>(ei, mode, cnt, N);
  scan1<<<N / 256, 256, 0, stream>>>(cnt, bsum);          // 512 blocks @ N=131072
  scan2<<<1, 512, 0, stream>>>(bsum, N / 256);            // nb = 512
  scan3<<<N / 256, 256, 0, stream>>>(cnt, bsum, baseA, N);
  scatter_eids<<<N / 256, 256, 0, stream>>>(ei, mode, baseA, cnt, rows_s, cols_s, N);

  const int nChunks = N * 32;
  prep_he<<<2 * nChunks / 256, 256, 0, stream>>>(h, h_t, e, e_t, nChunks);
  // GEMM1: PRPC = [h|e] @ [[A|D];[B|C]]^T + b1   (O=512, K=512)
  gemm_bt2<<<(N / 128) * 4, 256, 0, stream>>>(h_t, e_t, W1h, W1e, b1, PRPC, 512, 4, 16, (N / 128) * 4);
  // GEMM2: VU = h @ [V;U]^T + b2                 (O=512, K=256)
  gemm_bt2<<<(N / 128) * 4, 256, 0, stream>>>(h_t, h_t, W2t, W2t, b2, VU, 512, 4, 8, (N / 128) * 4);

  edge_stats<<<N / 64, 256, 0, stream>>>(PRPC, rows_s, cols_s, sums, sumsq);
  gather_sig_T<<<N / 64, 256, 0, stream>>>(e, PRPC, baseA, cols_s, ei, mode, VU,
                                           sums, sumsq, gamma, beta,
                                           accB, colsum, Traw, 1.0f / (float)N, N);
  finalize<<<nChunks / 256, 256, 0, stream>>>(accB, VU, colsum, Traw, outE, outH, nChunks);
}

// Round 9
// 539.554 us; speedup vs baseline: 1.1687x; 1.0799x over previous
//
#include <hip/hip_runtime.h>
#include <hip/hip_bf16.h>

// ---------------------------------------------------------------------------
// GatedNetwork: N = 131072 nodes == edges, C = 256 channels.
// Factorization: e_out[k] = PR[row[k]] + PC[col[k]],
//   PR = h@A^T + e@D^T + (Ab+Db),  PC = h@B^T + e@C^T + (Bb+Cb)
// Pipeline (13 dispatches):
//   prep_weights | memset(cnt) | sort(hist,scan1,scan2,scan3,scatter)
//   prep_he | GEMM1 PRPC | GEMM2 VU   (counted-vmcnt, 3-deep LDS pipeline)
//   edge_stats | gather_sig_T | finalize
// ---------------------------------------------------------------------------

typedef __attribute__((ext_vector_type(8))) short bf16x8;
typedef __attribute__((ext_vector_type(4))) float f32x4;

__device__ __forceinline__ float b2f(unsigned int lo16) {
  union { unsigned int u; float f; } c; c.u = lo16 << 16; return c.f;
}
__device__ __forceinline__ float lof(unsigned int u) { return b2f(u & 0xffffu); }
__device__ __forceinline__ float hif(unsigned int u) { return b2f(u >> 16); }
__device__ __forceinline__ unsigned int f2b(float f) {  // RNE f32->bf16
  union { float f; unsigned int u; } c; c.f = f;
  unsigned int u = c.u;
  u += 0x7fffu + ((u >> 16) & 1u);
  return u >> 16;
}

// --- prep: f32 row-major [M][256] -> bf16 tiled [M/16][32][16][8] ----------
__device__ __forceinline__ void prep_chunk(const float* __restrict__ src,
                                           unsigned short* __restrict__ dst, int g) {
  int mtile = g >> 9;
  int rem = g & 511;
  int r = rem >> 5, k8 = rem & 31;
  const float4* s = reinterpret_cast<const float4*>(src + (((size_t)mtile * 16 + r) << 8) + k8 * 8);
  float4 v0 = s[0], v1 = s[1];
  uint4 o;
  o.x = f2b(v0.x) | (f2b(v0.y) << 16);
  o.y = f2b(v0.z) | (f2b(v0.w) << 16);
  o.z = f2b(v1.x) | (f2b(v1.y) << 16);
  o.w = f2b(v1.z) | (f2b(v1.w) << 16);
  *reinterpret_cast<uint4*>(dst + ((size_t)mtile * 512 + k8 * 16 + r) * 8) = o;
}

__global__ __launch_bounds__(256) void prep_he(const float* __restrict__ h,
                                               unsigned short* __restrict__ h_t,
                                               const float* __restrict__ e,
                                               unsigned short* __restrict__ e_t,
                                               int nChunksEach) {
  int g = blockIdx.x * 256 + threadIdx.x;
  if (g < nChunksEach) prep_chunk(h, h_t, g);
  else if (g < 2 * nChunksEach) prep_chunk(e, e_t, g - nChunksEach);
}

// weights -> tiled bf16; block 0 also: bias pack, idx-mode, zero stats
__global__ __launch_bounds__(256) void prep_weights(
    const float* __restrict__ s0, const float* __restrict__ s1,
    const float* __restrict__ s2, const float* __restrict__ s3,
    const float* __restrict__ s4, const float* __restrict__ s5,
    unsigned short* __restrict__ W1h, unsigned short* __restrict__ W1e,
    unsigned short* __restrict__ W2t,
    const float* __restrict__ Ab, const float* __restrict__ Db,
    const float* __restrict__ Bb, const float* __restrict__ Cb,
    const float* __restrict__ Vb, const float* __restrict__ Ub,
    float* __restrict__ b1, float* __restrict__ b2,
    float* __restrict__ sums, float* __restrict__ sumsq,
    float* __restrict__ colsum, float* __restrict__ Traw,
    const int* __restrict__ ei, int* __restrict__ mode) {
  int g = blockIdx.x * 256 + threadIdx.x;
  if (blockIdx.x == 0) {
    const int t = threadIdx.x;
    b1[t] = Ab[t] + Db[t];
    b1[256 + t] = Bb[t] + Cb[t];
    b2[t] = Vb[t];
    b2[256 + t] = Ub[t];
    sums[t] = 0.f; sumsq[t] = 0.f; colsum[t] = 0.f; Traw[t] = 0.f;
    if (t == 0) {
      int m = 0;
#pragma unroll
      for (int i = 1; i < 64; i += 2) m |= ei[i];
      *mode = (m == 0) ? 1 : 0;
    }
  }
  int sel = g >> 13;
  int gg = g & 8191;
  const float* src; unsigned short* dst;
  switch (sel) {
    case 0: src = s0; dst = W1h; break;           // A
    case 1: src = s1; dst = W1h + 65536; break;   // B
    case 2: src = s2; dst = W1e; break;           // D
    case 3: src = s3; dst = W1e + 65536; break;   // C
    case 4: src = s4; dst = W2t; break;           // V
    default: src = s5; dst = W2t + 65536; break;  // U
  }
  prep_chunk(src, dst, gg);
}

// --- GEMM (two K-sources), counted-vmcnt 3-deep LDS pipeline ---------------
// kt<8 reads (Ah,Bh), kt>=8 reads (Ae,Be). ktSteps=8 -> single-source K=256.
// Per iter: vmcnt(4) [tile kt done, kt+1 in flight] -> s_barrier ->
//           stage(kt+2) -> ds_read+MFMA(tile kt). One barrier per K-step;
//           loads NEVER drained to 0 in steady state (T4, m218).
__global__ __launch_bounds__(256) void gemm_bt2(
    const unsigned short* __restrict__ Ah, const unsigned short* __restrict__ Ae,
    const unsigned short* __restrict__ Bh, const unsigned short* __restrict__ Be,
    const float* __restrict__ bias, unsigned short* __restrict__ Cmat,
    int O, int nColBlk, int ktSteps, int nBlk) {
  __shared__ char lds[49152];  // A0/A1/A2 at 0/8K/16K, B0/B1/B2 at 24K/32K/40K
  const int cpx = nBlk >> 3;
  const int hw = blockIdx.x;
  const int bid = (hw % 8) * cpx + hw / 8;  // bijective XCD swizzle (nBlk%8==0)
  const int colBlk = bid % nColBlk;
  const int rowBlk = bid / nColBlk;
  const int tid = threadIdx.x;
  const int w = tid >> 6, lane = tid & 63;
  const int wm = w >> 1, wn = w & 1;

  const size_t aTileOff = (size_t)(rowBlk * 8 + w * 2) * 8192 + lane * 16;
  const size_t bTileOff = (size_t)(colBlk * 8 + w * 2) * 8192 + lane * 16;
  const int wOff0 = (w * 2) * 1024;
  const int wOff1 = (w * 2 + 1) * 1024;

  f32x4 acc[4][4] = {};

  auto stage = [&](int kt, char* bufA, char* bufB) {
    const char* Ab_ = (const char*)(kt < 8 ? Ah : Ae) + aTileOff + (size_t)(kt & 7) * 1024;
    const char* Bb_ = (const char*)(kt < 8 ? Bh : Be) + bTileOff + (size_t)(kt & 7) * 1024;
    __builtin_amdgcn_global_load_lds((const __attribute__((address_space(1))) void*)Ab_,
                                     (__attribute__((address_space(3))) void*)(bufA + wOff0), 16, 0, 0);
    __builtin_amdgcn_global_load_lds((const __attribute__((address_space(1))) void*)(Ab_ + 8192),
                                     (__attribute__((address_space(3))) void*)(bufA + wOff1), 16, 0, 0);
    __builtin_amdgcn_global_load_lds((const __attribute__((address_space(1))) void*)Bb_,
                                     (__attribute__((address_space(3))) void*)(bufB + wOff0), 16, 0, 0);
    __builtin_amdgcn_global_load_lds((const __attribute__((address_space(1))) void*)(Bb_ + 8192),
                                     (__attribute__((address_space(3))) void*)(bufB + wOff1), 16, 0, 0);
  };
  auto computeFrom = [&](const char* bufA, const char* bufB) {
    bf16x8 a[4], b[4];
#pragma unroll
    for (int mi = 0; mi < 4; ++mi)
      a[mi] = *reinterpret_cast<const bf16x8*>(bufA + (wm * 4 + mi) * 1024 + lane * 16);
#pragma unroll
    for (int ni = 0; ni < 4; ++ni)
      b[ni] = *reinterpret_cast<const bf16x8*>(bufB + (wn * 4 + ni) * 1024 + lane * 16);
#pragma unroll
    for (int mi = 0; mi < 4; ++mi)
#pragma unroll
      for (int ni = 0; ni < 4; ++ni)
        acc[mi][ni] = __builtin_amdgcn_mfma_f32_16x16x32_bf16(a[mi], b[ni], acc[mi][ni], 0, 0, 0);
  };

  char* A0 = lds;          char* A1 = lds + 8192;   char* A2 = lds + 16384;
  char* B0 = lds + 24576;  char* B1 = lds + 32768;  char* B2 = lds + 40960;

  stage(0, A0, B0);   // 4 loads/wave in flight
  stage(1, A1, B1);   // 8 in flight
  char *Ac = A0, *An = A1, *Aq = A2;
  char *Bc = B0, *Bn = B1, *Bq = B2;

#pragma unroll 1
  for (int kt = 0; kt < ktSteps; ++kt) {
    if (kt + 1 < ktSteps) {
      asm volatile("s_waitcnt vmcnt(4)" ::: "memory");  // tile kt done; kt+1 flying
    } else {
      asm volatile("s_waitcnt vmcnt(0)" ::: "memory");  // last tile: full drain
    }
    __builtin_amdgcn_s_barrier();
    asm volatile("" ::: "memory");   // fence: nothing moves above the barrier
    __builtin_amdgcn_sched_barrier(0);
    if (kt + 2 < ktSteps) stage(kt + 2, Aq, Bq);  // overwrites tile kt-1's buf:
                                                  // all waves' reads of it done
                                                  // before they reached this bar
    computeFrom(Ac, Bc);
    char* tA = Ac; Ac = An; An = Aq; Aq = tA;
    char* tB = Bc; Bc = Bn; Bn = Bq; Bq = tB;
  }

  const int rb = rowBlk * 128 + wm * 64 + ((lane >> 4) << 2);
  const int cb = colBlk * 128 + wn * 64 + (lane & 15);
#pragma unroll
  for (int mi = 0; mi < 4; ++mi) {
#pragma unroll
    for (int ni = 0; ni < 4; ++ni) {
      const int coln = cb + ni * 16;
      const float bz = bias[coln];
      const size_t base = (size_t)(rb + mi * 16) * O + coln;
#pragma unroll
      for (int r = 0; r < 4; ++r)
        Cmat[base + (size_t)r * O] = (unsigned short)f2b(acc[mi][ni][r] + bz);
    }
  }
}

// --- BN batch stats over e_out[p] = PR[rows_s[p]] + PC[cols_s[p]] ----------
__global__ __launch_bounds__(256) void edge_stats(
    const unsigned short* __restrict__ PRPC,
    const int* __restrict__ rows_s, const int* __restrict__ cols_s,
    float* __restrict__ sums, float* __restrict__ sumsq) {
  __shared__ float red[8][256];
  const int c8 = threadIdx.x & 31;
  const int sub = threadIdx.x >> 5;
  float s[8], q[8];
#pragma unroll
  for (int j = 0; j < 8; ++j) { s[j] = 0.f; q[j] = 0.f; }
#pragma unroll 1
  for (int grp = 0; grp < 2; ++grp) {
    const int kb = blockIdx.x * 64 + grp * 32 + sub * 4;
    int r[4], cj[4];
#pragma unroll
    for (int u = 0; u < 4; ++u) { r[u] = rows_s[kb + u]; cj[u] = cols_s[kb + u]; }
    uint4 pr[4], pc[4];
#pragma unroll
    for (int u = 0; u < 4; ++u)
      pr[u] = *reinterpret_cast<const uint4*>(PRPC + (size_t)r[u] * 512 + c8 * 8);
#pragma unroll
    for (int u = 0; u < 4; ++u)
      pc[u] = *reinterpret_cast<const uint4*>(PRPC + (size_t)cj[u] * 512 + 256 + c8 * 8);
#pragma unroll
    for (int u = 0; u < 4; ++u) {
      const unsigned int rw[4] = {pr[u].x, pr[u].y, pr[u].z, pr[u].w};
      const unsigned int cw[4] = {pc[u].x, pc[u].y, pc[u].z, pc[u].w};
#pragma unroll
      for (int p4 = 0; p4 < 4; ++p4) {
        const float v0 = lof(rw[p4]) + lof(cw[p4]);
        const float v1 = hif(rw[p4]) + hif(cw[p4]);
        s[2 * p4] += v0;     q[2 * p4] += v0 * v0;
        s[2 * p4 + 1] += v1; q[2 * p4 + 1] += v1 * v1;
      }
    }
  }
#pragma unroll
  for (int j = 0; j < 8; ++j) red[sub][c8 * 8 + j] = s[j];
  __syncthreads();
  {
    const int c = threadIdx.x;
    float t = 0.f;
#pragma unroll
    for (int u2 = 0; u2 < 8; ++u2) t += red[u2][c];
    atomicAdd(sums + c, t);
  }
  __syncthreads();
#pragma unroll
  for (int j = 0; j < 8; ++j) red[sub][c8 * 8 + j] = q[j];
  __syncthreads();
  {
    const int c = threadIdx.x;
    float t = 0.f;
#pragma unroll
    for (int u2 = 0; u2 < 8; ++u2) t += red[u2][c];
    atomicAdd(sumsq + c, t);
  }
}

// --- counting sort of edges by row -----------------------------------------
__global__ __launch_bounds__(256) void hist_rows(const int* __restrict__ ei,
                                                 const int* __restrict__ modep,
                                                 int* __restrict__ cnt, int Nn) {
  const int k = blockIdx.x * 256 + threadIdx.x;
  if (k >= Nn) return;
  const int row = (*modep) ? ei[2 * k] : ei[k];
  atomicAdd(&cnt[row], 1);
}

__global__ __launch_bounds__(256) void scan1(const int* __restrict__ cnt,
                                             int* __restrict__ bsum) {
  __shared__ int red[256];
  const int t = threadIdx.x;
  red[t] = cnt[blockIdx.x * 256 + t];
  __syncthreads();
#pragma unroll
  for (int s = 128; s > 0; s >>= 1) {
    if (t < s) red[t] += red[t + s];
    __syncthreads();
  }
  if (t == 0) bsum[blockIdx.x] = red[0];
}

__global__ __launch_bounds__(512) void scan2(int* __restrict__ bsum, int nb) {
  __shared__ int tmp[512];
  const int t = threadIdx.x;
  const int own = (t < nb) ? bsum[t] : 0;
  tmp[t] = own;
  __syncthreads();
  for (int off = 1; off < 512; off <<= 1) {
    int v = (t >= off) ? tmp[t - off] : 0;
    __syncthreads();
    tmp[t] += v;
    __syncthreads();
  }
  if (t < nb) bsum[t] = tmp[t] - own;  // exclusive
}

__global__ __launch_bounds__(256) void scan3(const int* __restrict__ cnt,
                                             const int* __restrict__ bsum,
                                             int* __restrict__ base, int Nn) {
  __shared__ int tmp[256];
  const int t = threadIdx.x;
  const int gid = blockIdx.x * 256 + t;
  const int own = cnt[gid];
  tmp[t] = own;
  __syncthreads();
  for (int off = 1; off < 256; off <<= 1) {
    int v = (t >= off) ? tmp[t - off] : 0;
    __syncthreads();
    tmp[t] += v;
    __syncthreads();
  }
  base[gid] = tmp[t] - own + bsum[blockIdx.x];
  if (gid == 0) base[Nn] = Nn;  // E == N
}

__global__ __launch_bounds__(256) void scatter_eids(const int* __restrict__ ei,
                                                    const int* __restrict__ modep,
                                                    const int* __restrict__ base,
                                                    int* __restrict__ cnt,
                                                    int* __restrict__ rows_s,
                                                    int* __restrict__ cols_s, int Nn) {
  const int k = blockIdx.x * 256 + threadIdx.x;
  if (k >= Nn) return;
  int row, col;
  if (*modep) { row = ei[2 * k]; col = ei[2 * (Nn + k)]; }
  else        { row = ei[k];     col = ei[Nn + k]; }
  const int pos = base[row] + atomicAdd(&cnt[row], -1) - 1;
  rows_s[pos] = row;
  cols_s[pos] = col;
}

// --- fused: sig[i] = sigmoid(e[i] + sum_seg relu(sc*(PR[i]+PC[col])+sh))
//     accB[i] = bf16(sig); colsum += sig; Traw += sig * HV[col_orig[i]] -----
#define GCAP 1024
__global__ __launch_bounds__(256) void gather_sig_T(
    const float* __restrict__ e, const unsigned short* __restrict__ PRPC,
    const int* __restrict__ base, const int* __restrict__ cols_s,
    const int* __restrict__ ei, const int* __restrict__ modep,
    const unsigned short* __restrict__ VU,
    const float* __restrict__ sums, const float* __restrict__ sumsq,
    const float* __restrict__ gamma, const float* __restrict__ beta,
    unsigned short* __restrict__ accB, float* __restrict__ colsum,
    float* __restrict__ Traw, float invE, int Nn) {
  __shared__ float red[4][256];
  __shared__ int colsL[GCAP];
  __shared__ int baseL[65];
  const int lane = threadIdx.x & 63, w = threadIdx.x >> 6;
  const int n0 = blockIdx.x * 64;
  if (threadIdx.x < 65) baseL[threadIdx.x] = base[n0 + threadIdx.x];
  __syncthreads();
  const int bstart = baseL[0];
  const int bcount = baseL[64] - bstart;
  for (int qq = threadIdx.x; qq < bcount && qq < GCAP; qq += 256)
    colsL[qq] = cols_s[bstart + qq];
  const float4 sm = *reinterpret_cast<const float4*>(sums + lane * 4);
  const float4 sq = *reinterpret_cast<const float4*>(sumsq + lane * 4);
  const float4 gm = *reinterpret_cast<const float4*>(gamma + lane * 4);
  const float4 bt = *reinterpret_cast<const float4*>(beta + lane * 4);
  float4 sc, sh;
  {
    const float mx = sm.x * invE, my = sm.y * invE, mz = sm.z * invE, mw = sm.w * invE;
    sc.x = gm.x * rsqrtf(fmaxf(sq.x * invE - mx * mx, 0.f) + 1e-5f);
    sc.y = gm.y * rsqrtf(fmaxf(sq.y * invE - my * my, 0.f) + 1e-5f);
    sc.z = gm.z * rsqrtf(fmaxf(sq.z * invE - mz * mz, 0.f) + 1e-5f);
    sc.w = gm.w * rsqrtf(fmaxf(sq.w * invE - mw * mw, 0.f) + 1e-5f);
    sh.x = bt.x - mx * sc.x; sh.y = bt.y - my * sc.y;
    sh.z = bt.z - mz * sc.z; sh.w = bt.w - mw * sc.w;
  }
  __syncthreads();
  const int mode = *modep;
  float s0 = 0.f, s1 = 0.f, s2 = 0.f, s3 = 0.f;
  float t0 = 0.f, t1 = 0.f, t2 = 0.f, t3 = 0.f;
  const int i0 = n0 + w * 16;
  int p = baseL[w * 16];
  const int pendW = baseL[w * 16 + 16];
  uint2 pcn; pcn.x = 0; pcn.y = 0;
  if (p < pendW) {
    const int q0 = p - bstart;
    const int cj = (q0 < GCAP) ? colsL[q0] : cols_s[p];
    pcn = *reinterpret_cast<const uint2*>(PRPC + (size_t)cj * 512 + 256 + lane * 4);
  }
  float4 ev = *reinterpret_cast<const float4*>(e + (size_t)i0 * 256 + lane * 4);
  uint2 prv = *reinterpret_cast<const uint2*>(PRPC + (size_t)i0 * 512 + lane * 4);
#pragma unroll 1
  for (int it = 0; it < 16; ++it) {
    const int i = i0 + it;
    const int colT = mode ? ei[2 * (Nn + i)] : ei[Nn + i];
    const uint2 hv = *reinterpret_cast<const uint2*>(VU + (size_t)colT * 512 + lane * 4);
    float4 v = ev;
    const uint2 pr = prv;
    if (it + 1 < 16) {
      ev = *reinterpret_cast<const float4*>(e + (size_t)(i + 1) * 256 + lane * 4);
      prv = *reinterpret_cast<const uint2*>(PRPC + (size_t)(i + 1) * 512 + lane * 4);
    }
    const float pr0 = lof(pr.x), pr1 = hif(pr.x), pr2 = lof(pr.y), pr3 = hif(pr.y);
    const int pe = baseL[w * 16 + it + 1];
#pragma unroll 1
    while (p < pe) {
      const uint2 pc = pcn;
      if (p + 1 < pendW) {
        const int qn = p + 1 - bstart;
        const int cj = (qn < GCAP) ? colsL[qn] : cols_s[p + 1];
        pcn = *reinterpret_cast<const uint2*>(PRPC + (size_t)cj * 512 + 256 + lane * 4);
      }
      v.x += fmaxf(fmaf(sc.x, pr0 + lof(pc.x), sh.x), 0.f);
      v.y += fmaxf(fmaf(sc.y, pr1 + hif(pc.x), sh.y), 0.f);
      v.z += fmaxf(fmaf(sc.z, pr2 + lof(pc.y), sh.z), 0.f);
      v.w += fmaxf(fmaf(sc.w, pr3 + hif(pc.y), sh.w), 0.f);
      ++p;
    }
    v.x = 1.f / (1.f + __expf(-v.x));
    v.y = 1.f / (1.f + __expf(-v.y));
    v.z = 1.f / (1.f + __expf(-v.z));
    v.w = 1.f / (1.f + __expf(-v.w));
    uint2 ob;
    ob.x = f2b(v.x) | (f2b(v.y) << 16);
    ob.y = f2b(v.z) | (f2b(v.w) << 16);
    *reinterpret_cast<uint2*>(accB + (size_t)i * 256 + lane * 4) = ob;
    s0 += v.x; s1 += v.y; s2 += v.z; s3 += v.w;
    t0 += v.x * lof(hv.x); t1 += v.y * hif(hv.x);
    t2 += v.z * lof(hv.y); t3 += v.w * hif(hv.y);
  }
  red[w][lane * 4 + 0] = s0;
  red[w][lane * 4 + 1] = s1;
  red[w][lane * 4 + 2] = s2;
  red[w][lane * 4 + 3] = s3;
  __syncthreads();
  {
    const int c = threadIdx.x;
    atomicAdd(colsum + c, red[0][c] + red[1][c] + red[2][c] + red[3][c]);
  }
  __syncthreads();
  red[w][lane * 4 + 0] = t0;
  red[w][lane * 4 + 1] = t1;
  red[w][lane * 4 + 2] = t2;
  red[w][lane * 4 + 3] = t3;
  __syncthreads();
  {
    const int c = threadIdx.x;
    atomicAdd(Traw + c, red[0][c] + red[1][c] + red[2][c] + red[3][c]);
  }
}

// --- finalize: outE[i] = accB[i]*iv ; outH[i] = relu(HU[i] + iv*Traw) ------
__global__ __launch_bounds__(256) void finalize(
    const unsigned short* __restrict__ accB, const unsigned short* __restrict__ VU,
    const float* __restrict__ colsum, const float* __restrict__ Traw,
    float* __restrict__ outE, float* __restrict__ outH, int nChunks) {
  const int g = blockIdx.x * 256 + threadIdx.x;
  if (g >= nChunks) return;
  const int i = g >> 5, c8 = g & 31;
  const float4 cs0 = *reinterpret_cast<const float4*>(colsum + c8 * 8);
  const float4 cs1 = *reinterpret_cast<const float4*>(colsum + c8 * 8 + 4);
  const float4 tr0 = *reinterpret_cast<const float4*>(Traw + c8 * 8);
  const float4 tr1 = *reinterpret_cast<const float4*>(Traw + c8 * 8 + 4);
  float iv[8] = {1.f / (cs0.x + 1e-5f), 1.f / (cs0.y + 1e-5f),
                 1.f / (cs0.z + 1e-5f), 1.f / (cs0.w + 1e-5f),
                 1.f / (cs1.x + 1e-5f), 1.f / (cs1.y + 1e-5f),
                 1.f / (cs1.z + 1e-5f), 1.f / (cs1.w + 1e-5f)};
  float tt[8] = {tr0.x * iv[0], tr0.y * iv[1], tr0.z * iv[2], tr0.w * iv[3],
                 tr1.x * iv[4], tr1.y * iv[5], tr1.z * iv[6], tr1.w * iv[7]};
  const uint4 sb = *reinterpret_cast<const uint4*>(accB + (size_t)i * 256 + c8 * 8);
  const unsigned int sw[4] = {sb.x, sb.y, sb.z, sb.w};
  float4 e0, e1;
  e0.x = lof(sw[0]) * iv[0]; e0.y = hif(sw[0]) * iv[1];
  e0.z = lof(sw[1]) * iv[2]; e0.w = hif(sw[1]) * iv[3];
  e1.x = lof(sw[2]) * iv[4]; e1.y = hif(sw[2]) * iv[5];
  e1.z = lof(sw[3]) * iv[6]; e1.w = hif(sw[3]) * iv[7];
  float4* qe = reinterpret_cast<float4*>(outE + (size_t)i * 256 + c8 * 8);
  qe[0] = e0; qe[1] = e1;
  const uint4 hu = *reinterpret_cast<const uint4*>(VU + (size_t)i * 512 + 256 + c8 * 8);
  float4 o0, o1;
  o0.x = fmaxf(lof(hu.x) + tt[0], 0.f);
  o0.y = fmaxf(hif(hu.x) + tt[1], 0.f);
  o0.z = fmaxf(lof(hu.y) + tt[2], 0.f);
  o0.w = fmaxf(hif(hu.y) + tt[3], 0.f);
  o1.x = fmaxf(lof(hu.z) + tt[4], 0.f);
  o1.y = fmaxf(hif(hu.z) + tt[5], 0.f);
  o1.z = fmaxf(lof(hu.w) + tt[6], 0.f);
  o1.w = fmaxf(hif(hu.w) + tt[7], 0.f);
  float4* qh = reinterpret_cast<float4*>(outH + (size_t)i * 256 + c8 * 8);
  qh[0] = o0; qh[1] = o1;
}

extern "C" void kernel_launch(void* const* d_in, const int* in_sizes, int n_in,
                              void* d_out, int out_size, void* d_ws, size_t ws_size,
                              hipStream_t stream) {
  const float* h     = (const float*)d_in[0];
  const int*   ei    = (const int*)d_in[1];
  const float* e     = (const float*)d_in[2];
  const float* Aw    = (const float*)d_in[3];
  const float* Ab    = (const float*)d_in[4];
  const float* Bw    = (const float*)d_in[5];
  const float* Bb    = (const float*)d_in[6];
  const float* Cw    = (const float*)d_in[7];
  const float* Cb    = (const float*)d_in[8];
  const float* Dw    = (const float*)d_in[9];
  const float* Db    = (const float*)d_in[10];
  const float* gamma = (const float*)d_in[11];
  const float* beta  = (const float*)d_in[12];
  const float* Uw    = (const float*)d_in[13];
  const float* Ub    = (const float*)d_in[14];
  const float* Vw    = (const float*)d_in[15];
  const float* Vb    = (const float*)d_in[16];
  const int N = in_sizes[0] / 256;  // 131072

  char* ws = (char*)d_ws;
  unsigned short* W1h = (unsigned short*)(ws + 0x0);       // [A;B] tiled, 256 KiB
  unsigned short* W1e = (unsigned short*)(ws + 0x40000);   // [D;C] tiled, 256 KiB
  unsigned short* W2t = (unsigned short*)(ws + 0x80000);   // [V;U] tiled, 256 KiB
  float* b1     = (float*)(ws + 0xC0000);
  float* b2     = (float*)(ws + 0xC0800);
  float* sums   = (float*)(ws + 0xC1000);
  float* sumsq  = (float*)(ws + 0xC1400);
  float* colsum = (float*)(ws + 0xC1800);
  float* Traw   = (float*)(ws + 0xC1C00);
  int*   mode   = (int*)(ws + 0xC2C00);
  unsigned short* h_t  = (unsigned short*)(ws + 0x100000);   // 64 MiB
  unsigned short* e_t  = (unsigned short*)(ws + 0x4100000);  // 64 MiB
  unsigned short* PRPC = (unsigned short*)(ws + 0x8100000);  // 128 MiB
  unsigned short* VU   = (unsigned short*)(ws + 0x10100000); // 128 MiB
  unsigned short* accB = (unsigned short*)(ws + 0x100000);   // overlays h_t (dead after GEMMs)
  int* cnt    = (int*)(ws + 0x18100000);
  int* baseA  = (int*)(ws + 0x18180000);
  int* rows_s = (int*)(ws + 0x18210000);
  int* cols_s = (int*)(ws + 0x18290000);
  int* bsum   = (int*)(ws + 0x18310000);

  float* outH = (float*)d_out;
  float* outE = outH + (size_t)N * 256;

  hipMemsetAsync(cnt, 0, (size_t)N * 4, stream);
  prep_weights<<<192, 256, 0, stream>>>(Aw, Bw, Dw, Cw, Vw, Uw, W1h, W1e, W2t,
                                        Ab, Db, Bb, Cb, Vb, Ub, b1, b2,
                                        sums, sumsq, colsum, Traw, ei, mode);

  // counting sort of edges by row
  hist_rows<<<N / 256, 256, 0, stream>>>(ei, mode, cnt, N);
  scan1<<<N / 256, 256, 0, stream>>>(cnt, bsum);          // 512 blocks @ N=131072
  scan2<<<1, 512, 0, stream>>>(bsum, N / 256);            // nb = 512
  scan3<<<N / 256, 256, 0, stream>>>(cnt, bsum, baseA, N);
  scatter_eids<<<N / 256, 256, 0, stream>>>(ei, mode, baseA, cnt, rows_s, cols_s, N);

  const int nChunks = N * 32;
  prep_he<<<2 * nChunks / 256, 256, 0, stream>>>(h, h_t, e, e_t, nChunks);
  // GEMM1: PRPC = [h|e] @ [[A|D];[B|C]]^T + b1   (O=512, K=512)
  gemm_bt2<<<(N / 128) * 4, 256, 0, stream>>>(h_t, e_t, W1h, W1e, b1, PRPC, 512, 4, 16, (N / 128) * 4);
  // GEMM2: VU = h @ [V;U]^T + b2                 (O=512, K=256)
  gemm_bt2<<<(N / 128) * 4, 256, 0, stream>>>(h_t, h_t, W2t, W2t, b2, VU, 512, 4, 8, (N / 128) * 4);

  edge_stats<<<N / 64, 256, 0, stream>>>(PRPC, rows_s, cols_s, sums, sumsq);
  gather_sig_T<<<N / 64, 256, 0, stream>>>(e, PRPC, baseA, cols_s, ei, mode, VU,
                                           sums, sumsq, gamma, beta,
                                           accB, colsum, Traw, 1.0f / (float)N, N);
  finalize<<<nChunks / 256, 256, 0, stream>>>(accB, VU, colsum, Traw, outE, outH, nChunks);
}